// Round 13
// baseline (37.933 us; speedup 1.0000x reference)
//
#include <hip/hip_runtime.h>
#include <hip/hip_bf16.h>

#define B_ 8
#define D_ 64
#define N_ 4096
#define M_ 4096
#define B3N (B_*3*N_)

// exp(s/8) = exp2(s * 0.125 * log2(e)) ; SCALE2 folded into Q prepass
#define SCALE2 0.18033688011112042f

typedef short bf16x8 __attribute__((ext_vector_type(8)));
typedef float f32x4 __attribute__((ext_vector_type(4)));
typedef __fp16 half2v __attribute__((ext_vector_type(2)));
typedef __fp16 half4v __attribute__((ext_vector_type(4)));
typedef unsigned int uint4v __attribute__((ext_vector_type(4)));

#if __has_builtin(__builtin_amdgcn_exp2f)
#define EXP2(x) __builtin_amdgcn_exp2f(x)
#else
#define EXP2(x) exp2f(x)
#endif

__device__ __forceinline__ unsigned fbits(float f) { return __builtin_bit_cast(unsigned, f); }

__device__ __forceinline__ unsigned pkbf(float hi, float lo) {
#if __has_builtin(__builtin_amdgcn_perm)
    return __builtin_amdgcn_perm(fbits(hi), fbits(lo), 0x07060302u);
#else
    return (fbits(hi) & 0xFFFF0000u) | (fbits(lo) >> 16);
#endif
}

__device__ __forceinline__ half2v pkhalf(float a, float b) {
#if __has_builtin(__builtin_amdgcn_cvt_pkrtz)
    return __builtin_bit_cast(half2v, __builtin_amdgcn_cvt_pkrtz(a, b));   // low=a, high=b
#else
    half2v r; r[0] = (__fp16)a; r[1] = (__fp16)b; return r;
#endif
}

// legacy-shape MFMA builtin (V4h x V4h -> V4f), verified compiles+correct r5.
#define MFMA_PV(a,b,c) __builtin_amdgcn_mfma_f32_16x16x16f16((a),(b),(c),0,0,0)

// HBM/L2 -> LDS direct DMA, 16B per lane. LDS dest = wave-uniform base +
// lane*16 (HW-applied); global src is per-lane. Our fragment-order layout is
// lane-linear on both sides by construction.
__device__ __forceinline__ void gload_lds16(const void* g, void* lds) {
    __builtin_amdgcn_global_load_lds(
        (const __attribute__((address_space(1))) unsigned int*)g,
        (__attribute__((address_space(3))) unsigned int*)(unsigned)(unsigned long long)lds,
        16, 0, 0);
}

// =============================================================================
// Swizzled layouts (fragment order):
//  emb: per (b, 16-point block): 2KB chunk, element (row lm, d=32h+8g+j) at
//       elem offset h*512 + (g*16+lm)*8 + j  -> load = base + lane*16B
//  th:  per (b, 16-row block): 512B, lane l -> {tgt_c[m0+4*(l>>4)+r]}_{r=0..3},
//       c = l&3 (c==3 -> 1.0) -> load = base + lane*8B
// =============================================================================

// ---- prep (swizzled): [b][d][p] f32 -> fragment-order bf16, scale on Q -----
__global__ __launch_bounds__(64) void prep_swz_kernel(const float* __restrict__ qe,
                                                      const float* __restrict__ ke,
                                                      unsigned short* __restrict__ qs,
                                                      unsigned short* __restrict__ ks)
{
    int blk = blockIdx.x;            // 0..1023 ; >=512 -> Q with scale
    bool isq = blk >= 512;
    int l  = blk & 511;
    int b  = l >> 6;
    int p  = ((l & 63) << 6) + threadIdx.x;
    const float* ip = (isq ? qe : ke) + (size_t)b * D_ * M_ + p;
    unsigned short* op = (isq ? qs : ks) + (size_t)b * M_ * D_
                       + (size_t)(p >> 4) * 1024 + (p & 15) * 8;
    float sc = isq ? SCALE2 : 1.0f;
    #pragma unroll
    for (int i = 0; i < 8; ++i) {    // d = 8i..8i+7 : h=i>>2, g=i&3
        float v[8];
        #pragma unroll
        for (int d = 0; d < 8; ++d) v[d] = ip[(size_t)(8*i + d) * M_] * sc;
        uint4v w;
        #pragma unroll
        for (int j = 0; j < 4; ++j) w[j] = pkbf(v[2*j+1], v[2*j]);
        *(uint4v*)(op + (i>>2)*512 + (i&3)*128) = w;
    }
}

// ---- prep3: src copy-through + tgt -> fragment-order fp16 table ------------
__global__ __launch_bounds__(256) void prep3_kernel(const float4* __restrict__ src4,
                                                    const float* __restrict__ tgt,
                                                    float4* __restrict__ out4,
                                                    __fp16* __restrict__ thswz)
{
    int blk = blockIdx.x;
    if (blk < 96) {                           // 96*256 = B*3*N/4 float4s
        int i = blk*256 + threadIdx.x;
        out4[i] = src4[i];
        return;
    }
    int unit = (blk - 96)*4 + (threadIdx.x >> 6);   // 0..2047 = b*256+mblk
    int b = unit >> 8, mblk = unit & 255;
    int l = threadIdx.x & 63;
    int c = l & 3, g = l >> 4;
    int m = mblk*16 + 4*g;
    float4 tv;
    if (c < 3) tv = *(const float4*)(tgt + ((size_t)b*3 + c)*M_ + m);
    else       tv = make_float4(1.f, 1.f, 1.f, 1.f);
    half2v a01 = pkhalf(tv.x, tv.y);
    half2v a23 = pkhalf(tv.z, tv.w);
    half4v af = __builtin_shufflevector(a01, a23, 0, 1, 2, 3);
    *(half4v*)((char*)thswz + (size_t)unit*512 + l*8) = af;
}

// ---- attn9: DMA-staged K (global_load_lds), 4-iter rounds, direct af -------
// 4 waves/block share one K stream via LDS. Per round: each wave issues 4
// global_load_lds (16KB total), computes 4 iterations (128 m-rows), 1 barrier.
// af read directly from L2 per wave (512B coalesced). No reg staging.
template<int S>
__global__ __launch_bounds__(256, 4)
void attn9_kernel(const unsigned short* __restrict__ qswz,
                  const unsigned short* __restrict__ kswz,
                  const __fp16* __restrict__ thswz,
                  float* __restrict__ partials)
{
    __shared__ __align__(16) unsigned char kbuf[2][16384];

    const int lane = threadIdx.x & 63;
    const int wave = threadIdx.x >> 6;
    const int lm = lane & 15, g = lane >> 4;
    const int b = blockIdx.z, slice = blockIdx.y;
    const int n0 = blockIdx.x * 256 + wave * 64;
    const int mchunk = M_ / S, mbase = slice * mchunk;

    // Q fragments (per-wave, VMEM once): 4 blocks of 2KB from block n0/16
    const char* qp = (const char*)qswz
                   + ((size_t)b * N_ * D_ + (size_t)(n0 >> 4) * 1024) * 2;
    bf16x8 qf[4][2];
    #pragma unroll
    for (int f = 0; f < 4; ++f) {
        qf[f][0] = *(const bf16x8*)(qp + f*2048 + lane*16);
        qf[f][1] = *(const bf16x8*)(qp + f*2048 + 1024 + lane*16);
    }

    const char* kp = (const char*)kswz
                   + ((size_t)b * M_ * D_ + (size_t)(mbase >> 4) * 1024) * 2
                   + lane*16;
    const char* tp = (const char*)thswz
                   + ((size_t)b * (M_/16) + (size_t)(mbase >> 4)) * 512;

    // prologue: stage round 0 (wave w -> chunks w*4 .. w*4+3)
    #pragma unroll
    for (int i = 0; i < 4; ++i)
        gload_lds16(kp + wave*4096 + i*1024, kbuf[0] + wave*4096 + i*1024);
    __syncthreads();   // compiler drains vmcnt(0) before s_barrier

    f32x4 D2[4] = {{0,0,0,0},{0,0,0,0},{0,0,0,0},{0,0,0,0}};

    auto compute = [&](bf16x8 kA, bf16x8 kB, half4v aF) {
        #pragma unroll
        for (int f = 0; f < 4; ++f) {
            f32x4 c4 = {0,0,0,0};
            c4 = __builtin_amdgcn_mfma_f32_16x16x32_bf16(kA, qf[f][0], c4, 0, 0, 0);
            c4 = __builtin_amdgcn_mfma_f32_16x16x32_bf16(kB, qf[f][1], c4, 0, 0, 0);
            float e0 = EXP2(c4[0]);
            float e1 = EXP2(c4[1]);
            float e2 = EXP2(c4[2]);
            float e3 = EXP2(c4[3]);
            half2v p01 = pkhalf(e0, e1);
            half2v p23 = pkhalf(e2, e3);
            half4v pbf = __builtin_shufflevector(p01, p23, 0, 1, 2, 3);
            D2[f] = MFMA_PV(aF, pbf, D2[f]);
        }
    };

    int cur = 0;
    const int rounds = mchunk / 128;   // 4 (4 iters x 32 m-rows per round)
    for (int r = 0; r < rounds; ++r) {
        if (r < rounds - 1) {
            const char* ksrc = kp + (r+1)*16384 + wave*4096;
            #pragma unroll
            for (int i = 0; i < 4; ++i)
                gload_lds16(ksrc + i*1024, kbuf[cur^1] + wave*4096 + i*1024);
        }
        #pragma unroll
        for (int it = 0; it < 4; ++it) {
            const unsigned char* kb4 = kbuf[cur] + it*4096;
            bf16x8 ka0 = *(const bf16x8*)(kb4 + 0*1024 + lane*16);
            bf16x8 kb0 = *(const bf16x8*)(kb4 + 1*1024 + lane*16);
            bf16x8 ka1 = *(const bf16x8*)(kb4 + 2*1024 + lane*16);
            bf16x8 kb1 = *(const bf16x8*)(kb4 + 3*1024 + lane*16);
            const char* tpi = tp + (r*4 + it)*1024;
            half4v af0 = *(const half4v*)(tpi + lane*8);
            half4v af1 = *(const half4v*)(tpi + 512 + lane*8);
            compute(ka0, kb0, af0);
            compute(ka1, kb1, af1);
        }
        __syncthreads();   // drains DMA (vmcnt) + LDS reads (lgkmcnt)
        cur ^= 1;
    }

    // PV result replicated across g-groups; group g writes partials row g
    // (row0=den=D[3], row1=x=D[0], row2=y=D[1], row3=z=D[2] -> sel=(g+3)&3)
    {
        size_t base = ((size_t)slice * B_ + b) * 4 * N_ + (size_t)g * N_;
        const int sel = (g + 3) & 3;
        #pragma unroll
        for (int f = 0; f < 4; ++f)
            partials[base + n0 + 16*f + lm] = D2[f][sel];
    }
}

// ---- old linear prep (for attn2 fallback tier only) ------------------------
__global__ __launch_bounds__(64) void prep_kernel(const float* __restrict__ qe,
                                                  const float* __restrict__ ke,
                                                  unsigned short* __restrict__ qb,
                                                  unsigned short* __restrict__ kb)
{
    int blk = blockIdx.x;
    bool isq = blk >= 512;
    int l  = blk & 511;
    int b  = l >> 6;
    int p  = ((l & 63) << 6) + threadIdx.x;
    const float* ip = (isq ? qe : ke) + (size_t)b * D_ * M_ + p;
    unsigned short* op = (isq ? qb : kb) + ((size_t)b * M_ + p) * D_;
    float sc = isq ? SCALE2 : 1.0f;
    #pragma unroll
    for (int i = 0; i < 8; ++i) {
        float v[8];
        #pragma unroll
        for (int d = 0; d < 8; ++d) v[d] = ip[(size_t)(8*i + d) * M_] * sc;
        uint4v w;
        #pragma unroll
        for (int j = 0; j < 4; ++j) w[j] = pkbf(v[2*j+1], v[2*j]);
        *(uint4v*)(op + 8*i) = w;
    }
}

// ---- 1-wave fallback (round-5 passing kernel, linear layout) ---------------
template<int S>
__global__ __launch_bounds__(64, 4)
void attn2_kernel(const unsigned short* __restrict__ qb,
                  const unsigned short* __restrict__ kb,
                  const float* __restrict__ tgt,
                  float* __restrict__ partials)
{
    const int t  = threadIdx.x, lm = t & 15, g = t >> 4;
    const int b  = blockIdx.z, slice = blockIdx.y, n0 = blockIdx.x * 64;
    const int mchunk = M_ / S, mbase = slice * mchunk;

    bf16x8 qf[4][2];
    #pragma unroll
    for (int f = 0; f < 4; ++f) {
        const unsigned short* qrow = qb + ((size_t)b * N_ + n0 + 16*f + lm) * D_ + 8*g;
        qf[f][0] = *(const bf16x8*)(qrow);
        qf[f][1] = *(const bf16x8*)(qrow + 32);
    }

    const bool isones = (lm & 3) == 3;
    const int  c_ld   = isones ? 2 : (lm & 3);
    half2v one2 = pkhalf(1.0f, 1.0f);
    const half4v ones4 = __builtin_shufflevector(one2, one2, 0, 1, 0, 1);

    const unsigned short* krow = kb + ((size_t)b * M_ + mbase + lm) * D_ + 8*g;
    const float* tp = tgt + ((size_t)b * 3 + c_ld) * M_ + mbase + 4*g;

    f32x4 D2[4] = {{0,0,0,0},{0,0,0,0},{0,0,0,0},{0,0,0,0}};

    for (int ms = 0; ms < mchunk; ms += 16) {
        bf16x8 ka  = *(const bf16x8*)(krow);
        bf16x8 kb8 = *(const bf16x8*)(krow + 32);
        f32x4 tv = *(const f32x4*)(tp);
        half2v a01 = pkhalf(tv[0], tv[1]);
        half2v a23 = pkhalf(tv[2], tv[3]);
        half4v afr = __builtin_shufflevector(a01, a23, 0, 1, 2, 3);
        afr = isones ? ones4 : afr;

        #pragma unroll
        for (int f = 0; f < 4; ++f) {
            f32x4 c4 = {0,0,0,0};
            c4 = __builtin_amdgcn_mfma_f32_16x16x32_bf16(ka,  qf[f][0], c4, 0, 0, 0);
            c4 = __builtin_amdgcn_mfma_f32_16x16x32_bf16(kb8, qf[f][1], c4, 0, 0, 0);
            float e0 = EXP2(c4[0]);
            float e1 = EXP2(c4[1]);
            float e2 = EXP2(c4[2]);
            float e3 = EXP2(c4[3]);
            half2v p01 = pkhalf(e0, e1);
            half2v p23 = pkhalf(e2, e3);
            half4v pbf = __builtin_shufflevector(p01, p23, 0, 1, 2, 3);
            D2[f] = MFMA_PV(afr, pbf, D2[f]);
        }
        krow += 16 * D_;
        tp   += 16;
    }

    if (t < 16) {
        size_t base = ((size_t)slice * B_ + b) * 4 * N_;
        #pragma unroll
        for (int f = 0; f < 4; ++f) {
            int n = n0 + 16*f + t;
            partials[base + 0*N_ + n] = D2[f][3];
            partials[base + 1*N_ + n] = D2[f][0];
            partials[base + 2*N_ + n] = D2[f][1];
            partials[base + 3*N_ + n] = D2[f][2];
        }
    }
}

// ---- epilogue kernels -------------------------------------------------------
__global__ void copy_kernel(const float4* __restrict__ src, float4* __restrict__ out) {
    int i = blockIdx.x*256 + threadIdx.x;   // grid = 96
    out[i] = src[i];
}

template<int S>
__global__ void finalize_kernel(const float* __restrict__ ws, float* __restrict__ out) {
    int tid = blockIdx.x*256 + threadIdx.x;  // B*N threads
    int b = tid >> 12;
    int n = tid & (N_-1);
    float den = 0.f, x = 0.f, y = 0.f, z = 0.f;
    #pragma unroll
    for (int s = 0; s < S; ++s) {
        size_t base = ((size_t)s*B_ + b)*4*N_ + n;
        den += ws[base];
        x   += ws[base + 1*N_];
        y   += ws[base + 2*N_];
        z   += ws[base + 3*N_];
    }
    float inv = 1.0f/den;
    out[B3N + ((size_t)b*3 + 0)*N_ + n] = x*inv;
    out[B3N + ((size_t)b*3 + 1)*N_ + n] = y*inv;
    out[B3N + ((size_t)b*3 + 2)*N_ + n] = z*inv;
}

extern "C" void kernel_launch(void* const* d_in, const int* in_sizes, int n_in,
                              void* d_out, int out_size, void* d_ws, size_t ws_size,
                              hipStream_t stream) {
    const float* qe  = (const float*)d_in[0];   // src_embedding [B,D,N]
    const float* ke  = (const float*)d_in[1];   // tgt_embedding [B,D,M]
    const float* src = (const float*)d_in[2];   // src [B,3,N]
    const float* tg  = (const float*)d_in[3];   // tgt [B,3,M]
    float* out = (float*)d_out;

    const size_t embElems = (size_t)B_ * M_ * D_;             // 2M elems (4MB bf16)
    const size_t embBytes = 2 * embElems * 2;                 // 8 MB (q+k)
    const size_t thBytes  = (size_t)B_ * 256 * 512;           // 1 MB swizzled th
    const size_t partB8   = (size_t)8 * B_ * 4 * N_ * 4;      // 4 MB
    const size_t needSwz  = embBytes + thBytes + partB8;      // ~13 MB
    const size_t needOld  = embBytes + partB8;                // ~12 MB

    unsigned short* kb16 = (unsigned short*)d_ws;
    unsigned short* qb16 = kb16 + embElems;
    __fp16* thswz = (__fp16*)((char*)d_ws + embBytes);
    float* partialsNew = (float*)((char*)d_ws + embBytes + thBytes);
    float* partialsOld = (float*)((char*)d_ws + embBytes);

    if (ws_size >= needSwz) {
        prep_swz_kernel<<<1024, 64, 0, stream>>>(qe, ke, qb16, kb16);
        prep3_kernel<<<608, 256, 0, stream>>>((const float4*)src, tg, (float4*)out, thswz);
        dim3 grid(N_/256, 8, B_);   // 1024 blocks x 4 waves = 16 waves/CU
        attn9_kernel<8><<<grid, 256, 0, stream>>>(qb16, kb16, thswz, partialsNew);
        finalize_kernel<8><<<(B_*N_)/256, 256, 0, stream>>>(partialsNew, out);
    } else if (ws_size >= needOld) {
        copy_kernel<<<96, 256, 0, stream>>>((const float4*)src, (float4*)out);
        prep_kernel<<<1024, 64, 0, stream>>>(qe, ke, qb16, kb16);
        dim3 grid(N_/64, 8, B_);
        attn2_kernel<8><<<grid, 64, 0, stream>>>(qb16, kb16, tg, partialsOld);
        finalize_kernel<8><<<(B_*N_)/256, 256, 0, stream>>>(partialsOld, out);
    }
}

// Round 14
// 34.820 us; speedup vs baseline: 1.0894x; 1.0894x over previous
//
#include <hip/hip_runtime.h>
#include <hip/hip_bf16.h>

#define B_ 8
#define D_ 64
#define N_ 4096
#define M_ 4096
#define B3N (B_*3*N_)

// exp(s/8) = exp2(s * 0.125 * log2(e)) ; SCALE2 folded into Q prepass
#define SCALE2 0.18033688011112042f

typedef short bf16x8 __attribute__((ext_vector_type(8)));
typedef float f32x4 __attribute__((ext_vector_type(4)));
typedef __fp16 half2v __attribute__((ext_vector_type(2)));
typedef __fp16 half4v __attribute__((ext_vector_type(4)));
typedef unsigned int uint4v __attribute__((ext_vector_type(4)));

#if __has_builtin(__builtin_amdgcn_exp2f)
#define EXP2(x) __builtin_amdgcn_exp2f(x)
#else
#define EXP2(x) exp2f(x)
#endif

__device__ __forceinline__ unsigned fbits(float f) { return __builtin_bit_cast(unsigned, f); }

__device__ __forceinline__ unsigned pkbf(float hi, float lo) {
#if __has_builtin(__builtin_amdgcn_perm)
    return __builtin_amdgcn_perm(fbits(hi), fbits(lo), 0x07060302u);
#else
    return (fbits(hi) & 0xFFFF0000u) | (fbits(lo) >> 16);
#endif
}

__device__ __forceinline__ half2v pkhalf(float a, float b) {
#if __has_builtin(__builtin_amdgcn_cvt_pkrtz)
    return __builtin_bit_cast(half2v, __builtin_amdgcn_cvt_pkrtz(a, b));   // low=a, high=b
#else
    half2v r; r[0] = (__fp16)a; r[1] = (__fp16)b; return r;
#endif
}

// legacy-shape MFMA builtin (V4h x V4h -> V4f), verified compiles+correct r5.
#define MFMA_PV(a,b,c) __builtin_amdgcn_mfma_f32_16x16x16f16((a),(b),(c),0,0,0)

// HBM/L2 -> LDS direct DMA, 16B per lane. LDS dest = wave-uniform base +
// lane*16 (HW-applied); global src is per-lane (linear copy by construction).
__device__ __forceinline__ void gload_lds16(const void* g, void* lds) {
    __builtin_amdgcn_global_load_lds(
        (const __attribute__((address_space(1))) unsigned int*)g,
        (__attribute__((address_space(3))) unsigned int*)(unsigned)(unsigned long long)lds,
        16, 0, 0);
}

// =============================================================================
// Swizzled layouts (fragment order):
//  emb: per (b, 16-point block): 2KB chunk, element (row lm, d=32h+8g+j) at
//       elem offset h*512 + (g*16+lm)*8 + j  -> load = base + lane*16B
//  th:  per (b, 16-row block): 512B, lane l -> {tgt_c[m0+4*(l>>4)+r]}_{r=0..3},
//       c = l&3 (c==3 -> 1.0) -> load = base + lane*8B
// =============================================================================

// ---- fused prep: src copy + emb swizzle/cvt + th table, ONE launch ---------
// grid 864 x 256:
//   blk [0,256):   emb units blk*4 + (tid>>6) in [0,1024)  (>=512 -> Q, scaled)
//   blk [256,352): src copy (96*256 float4s)
//   blk [352,864): th units (blk-352)*4 + (tid>>6) in [0,2048)
__global__ __launch_bounds__(256)
void prep_all_kernel(const float* __restrict__ qe, const float* __restrict__ ke,
                     const float4* __restrict__ src4, const float* __restrict__ tgt,
                     unsigned short* __restrict__ qs, unsigned short* __restrict__ ks,
                     float4* __restrict__ out4, __fp16* __restrict__ thswz)
{
    const int blk = blockIdx.x;
    if (blk < 256) {
        int unit = blk*4 + (threadIdx.x >> 6);
        int t64  = threadIdx.x & 63;
        bool isq = unit >= 512;
        int l = unit & 511;
        int b = l >> 6;
        int p = ((l & 63) << 6) + t64;
        const float* ip = (isq ? qe : ke) + (size_t)b * D_ * M_ + p;
        unsigned short* op = (isq ? qs : ks) + (size_t)b * M_ * D_
                           + (size_t)(p >> 4) * 1024 + (p & 15) * 8;
        float sc = isq ? SCALE2 : 1.0f;
        #pragma unroll
        for (int i = 0; i < 8; ++i) {    // d = 8i..8i+7 : h=i>>2, g=i&3
            float v[8];
            #pragma unroll
            for (int d = 0; d < 8; ++d) v[d] = ip[(size_t)(8*i + d) * M_] * sc;
            uint4v w;
            #pragma unroll
            for (int j = 0; j < 4; ++j) w[j] = pkbf(v[2*j+1], v[2*j]);
            *(uint4v*)(op + (i>>2)*512 + (i&3)*128) = w;
        }
    } else if (blk < 352) {
        int i = (blk - 256)*256 + threadIdx.x;
        out4[i] = src4[i];
    } else {
        int unit = (blk - 352)*4 + (threadIdx.x >> 6);   // 0..2047 = b*256+mblk
        int b = unit >> 8, mblk = unit & 255;
        int l = threadIdx.x & 63;
        int c = l & 3, g = l >> 4;
        int m = mblk*16 + 4*g;
        float4 tv;
        if (c < 3) tv = *(const float4*)(tgt + ((size_t)b*3 + c)*M_ + m);
        else       tv = make_float4(1.f, 1.f, 1.f, 1.f);
        half2v a01 = pkhalf(tv.x, tv.y);
        half2v a23 = pkhalf(tv.z, tv.w);
        half4v af = __builtin_shufflevector(a01, a23, 0, 1, 2, 3);
        *(half4v*)((char*)thswz + (size_t)unit*512 + l*8) = af;
    }
}

// ---- attn10: DMA-staged K AND af, 4-iter rounds, setprio on MFMA clusters --
// 4 waves/block share one K+af stream via LDS (read once per block).
// Per round: each wave issues 4 K-DMAs (4KB) + 1 af-DMA (1KB); 4 iterations
// (128 m-rows) of compute; 1 barrier. LDS 40KB -> exactly 4 blocks/CU.
template<int S>
__global__ __launch_bounds__(256, 4)
void attn10_kernel(const unsigned short* __restrict__ qswz,
                   const unsigned short* __restrict__ kswz,
                   const __fp16* __restrict__ thswz,
                   float* __restrict__ partials)
{
    __shared__ __align__(16) unsigned char kbuf[2][16384];
    __shared__ __align__(16) unsigned char abuf[2][4096];

    const int lane = threadIdx.x & 63;
    const int wave = threadIdx.x >> 6;
    const int lm = lane & 15, g = lane >> 4;
    const int b = blockIdx.z, slice = blockIdx.y;
    const int n0 = blockIdx.x * 256 + wave * 64;
    const int mchunk = M_ / S, mbase = slice * mchunk;

    // Q fragments (per-wave, VMEM once): 4 blocks of 2KB from block n0/16
    const char* qp = (const char*)qswz
                   + ((size_t)b * N_ * D_ + (size_t)(n0 >> 4) * 1024) * 2;
    bf16x8 qf[4][2];
    #pragma unroll
    for (int f = 0; f < 4; ++f) {
        qf[f][0] = *(const bf16x8*)(qp + f*2048 + lane*16);
        qf[f][1] = *(const bf16x8*)(qp + f*2048 + 1024 + lane*16);
    }

    const char* kp = (const char*)kswz
                   + ((size_t)b * M_ * D_ + (size_t)(mbase >> 4) * 1024) * 2
                   + lane*16;
    const char* tp = (const char*)thswz
                   + ((size_t)b * (M_/16) + (size_t)(mbase >> 4)) * 512
                   + lane*16;

    // prologue: stage round 0 (wave w -> K chunks w*4..w*4+3, af chunk w)
    #pragma unroll
    for (int i = 0; i < 4; ++i)
        gload_lds16(kp + wave*4096 + i*1024, kbuf[0] + wave*4096 + i*1024);
    gload_lds16(tp + wave*1024, abuf[0] + wave*1024);
    __syncthreads();   // compiler drains vmcnt(0) before s_barrier

    f32x4 D2[4] = {{0,0,0,0},{0,0,0,0},{0,0,0,0},{0,0,0,0}};

    auto compute = [&](bf16x8 kA, bf16x8 kB, half4v aF) {
        #pragma unroll
        for (int f = 0; f < 4; ++f) {
            f32x4 c4 = {0,0,0,0};
            c4 = __builtin_amdgcn_mfma_f32_16x16x32_bf16(kA, qf[f][0], c4, 0, 0, 0);
            c4 = __builtin_amdgcn_mfma_f32_16x16x32_bf16(kB, qf[f][1], c4, 0, 0, 0);
            float e0 = EXP2(c4[0]);
            float e1 = EXP2(c4[1]);
            float e2 = EXP2(c4[2]);
            float e3 = EXP2(c4[3]);
            half2v p01 = pkhalf(e0, e1);
            half2v p23 = pkhalf(e2, e3);
            half4v pbf = __builtin_shufflevector(p01, p23, 0, 1, 2, 3);
            D2[f] = MFMA_PV(aF, pbf, D2[f]);
        }
    };

    int cur = 0;
    const int rounds = mchunk / 128;   // 4 iters x 32 m-rows per round
    for (int r = 0; r < rounds; ++r) {
        if (r < rounds - 1) {
            const char* ksrc = kp + (r+1)*16384 + wave*4096;
            #pragma unroll
            for (int i = 0; i < 4; ++i)
                gload_lds16(ksrc + i*1024, kbuf[cur^1] + wave*4096 + i*1024);
            gload_lds16(tp + (r+1)*4096 + wave*1024, abuf[cur^1] + wave*1024);
        }
        #pragma unroll
        for (int it = 0; it < 4; ++it) {
            const unsigned char* kb4 = kbuf[cur] + it*4096;
            bf16x8 ka0 = *(const bf16x8*)(kb4 + 0*1024 + lane*16);
            bf16x8 kb0 = *(const bf16x8*)(kb4 + 1*1024 + lane*16);
            bf16x8 ka1 = *(const bf16x8*)(kb4 + 2*1024 + lane*16);
            bf16x8 kb1 = *(const bf16x8*)(kb4 + 3*1024 + lane*16);
            const unsigned char* ab = abuf[cur] + it*1024;
            half4v af0 = *(const half4v*)(ab + lane*8);
            half4v af1 = *(const half4v*)(ab + 512 + lane*8);
            __builtin_amdgcn_s_setprio(1);
            compute(ka0, kb0, af0);
            compute(ka1, kb1, af1);
            __builtin_amdgcn_s_setprio(0);
        }
        __syncthreads();   // drains DMA (vmcnt) + LDS reads (lgkmcnt)
        cur ^= 1;
    }

    // PV result replicated across g-groups; group g writes partials row g
    // (row0=den=D[3], row1=x=D[0], row2=y=D[1], row3=z=D[2] -> sel=(g+3)&3)
    {
        size_t base = ((size_t)slice * B_ + b) * 4 * N_ + (size_t)g * N_;
        const int sel = (g + 3) & 3;
        #pragma unroll
        for (int f = 0; f < 4; ++f)
            partials[base + n0 + 16*f + lm] = D2[f][sel];
    }
}

// ---- old linear prep (for attn2 fallback tier only) ------------------------
__global__ __launch_bounds__(64) void prep_kernel(const float* __restrict__ qe,
                                                  const float* __restrict__ ke,
                                                  unsigned short* __restrict__ qb,
                                                  unsigned short* __restrict__ kb)
{
    int blk = blockIdx.x;
    bool isq = blk >= 512;
    int l  = blk & 511;
    int b  = l >> 6;
    int p  = ((l & 63) << 6) + threadIdx.x;
    const float* ip = (isq ? qe : ke) + (size_t)b * D_ * M_ + p;
    unsigned short* op = (isq ? qb : kb) + ((size_t)b * M_ + p) * D_;
    float sc = isq ? SCALE2 : 1.0f;
    #pragma unroll
    for (int i = 0; i < 8; ++i) {
        float v[8];
        #pragma unroll
        for (int d = 0; d < 8; ++d) v[d] = ip[(size_t)(8*i + d) * M_] * sc;
        uint4v w;
        #pragma unroll
        for (int j = 0; j < 4; ++j) w[j] = pkbf(v[2*j+1], v[2*j]);
        *(uint4v*)(op + 8*i) = w;
    }
}

// ---- 1-wave fallback (round-5 passing kernel, linear layout) ---------------
template<int S>
__global__ __launch_bounds__(64, 4)
void attn2_kernel(const unsigned short* __restrict__ qb,
                  const unsigned short* __restrict__ kb,
                  const float* __restrict__ tgt,
                  float* __restrict__ partials)
{
    const int t  = threadIdx.x, lm = t & 15, g = t >> 4;
    const int b  = blockIdx.z, slice = blockIdx.y, n0 = blockIdx.x * 64;
    const int mchunk = M_ / S, mbase = slice * mchunk;

    bf16x8 qf[4][2];
    #pragma unroll
    for (int f = 0; f < 4; ++f) {
        const unsigned short* qrow = qb + ((size_t)b * N_ + n0 + 16*f + lm) * D_ + 8*g;
        qf[f][0] = *(const bf16x8*)(qrow);
        qf[f][1] = *(const bf16x8*)(qrow + 32);
    }

    const bool isones = (lm & 3) == 3;
    const int  c_ld   = isones ? 2 : (lm & 3);
    half2v one2 = pkhalf(1.0f, 1.0f);
    const half4v ones4 = __builtin_shufflevector(one2, one2, 0, 1, 0, 1);

    const unsigned short* krow = kb + ((size_t)b * M_ + mbase + lm) * D_ + 8*g;
    const float* tp = tgt + ((size_t)b * 3 + c_ld) * M_ + mbase + 4*g;

    f32x4 D2[4] = {{0,0,0,0},{0,0,0,0},{0,0,0,0},{0,0,0,0}};

    for (int ms = 0; ms < mchunk; ms += 16) {
        bf16x8 ka  = *(const bf16x8*)(krow);
        bf16x8 kb8 = *(const bf16x8*)(krow + 32);
        f32x4 tv = *(const f32x4*)(tp);
        half2v a01 = pkhalf(tv[0], tv[1]);
        half2v a23 = pkhalf(tv[2], tv[3]);
        half4v afr = __builtin_shufflevector(a01, a23, 0, 1, 2, 3);
        afr = isones ? ones4 : afr;

        #pragma unroll
        for (int f = 0; f < 4; ++f) {
            f32x4 c4 = {0,0,0,0};
            c4 = __builtin_amdgcn_mfma_f32_16x16x32_bf16(ka,  qf[f][0], c4, 0, 0, 0);
            c4 = __builtin_amdgcn_mfma_f32_16x16x32_bf16(kb8, qf[f][1], c4, 0, 0, 0);
            float e0 = EXP2(c4[0]);
            float e1 = EXP2(c4[1]);
            float e2 = EXP2(c4[2]);
            float e3 = EXP2(c4[3]);
            half2v p01 = pkhalf(e0, e1);
            half2v p23 = pkhalf(e2, e3);
            half4v pbf = __builtin_shufflevector(p01, p23, 0, 1, 2, 3);
            D2[f] = MFMA_PV(afr, pbf, D2[f]);
        }
        krow += 16 * D_;
        tp   += 16;
    }

    if (t < 16) {
        size_t base = ((size_t)slice * B_ + b) * 4 * N_;
        #pragma unroll
        for (int f = 0; f < 4; ++f) {
            int n = n0 + 16*f + t;
            partials[base + 0*N_ + n] = D2[f][3];
            partials[base + 1*N_ + n] = D2[f][0];
            partials[base + 2*N_ + n] = D2[f][1];
            partials[base + 3*N_ + n] = D2[f][2];
        }
    }
}

// ---- epilogue kernels -------------------------------------------------------
__global__ void copy_kernel(const float4* __restrict__ src, float4* __restrict__ out) {
    int i = blockIdx.x*256 + threadIdx.x;   // grid = 96
    out[i] = src[i];
}

template<int S>
__global__ void finalize_kernel(const float* __restrict__ ws, float* __restrict__ out) {
    int tid = blockIdx.x*256 + threadIdx.x;  // B*N threads
    int b = tid >> 12;
    int n = tid & (N_-1);
    float den = 0.f, x = 0.f, y = 0.f, z = 0.f;
    #pragma unroll
    for (int s = 0; s < S; ++s) {
        size_t base = ((size_t)s*B_ + b)*4*N_ + n;
        den += ws[base];
        x   += ws[base + 1*N_];
        y   += ws[base + 2*N_];
        z   += ws[base + 3*N_];
    }
    float inv = 1.0f/den;
    out[B3N + ((size_t)b*3 + 0)*N_ + n] = x*inv;
    out[B3N + ((size_t)b*3 + 1)*N_ + n] = y*inv;
    out[B3N + ((size_t)b*3 + 2)*N_ + n] = z*inv;
}

extern "C" void kernel_launch(void* const* d_in, const int* in_sizes, int n_in,
                              void* d_out, int out_size, void* d_ws, size_t ws_size,
                              hipStream_t stream) {
    const float* qe  = (const float*)d_in[0];   // src_embedding [B,D,N]
    const float* ke  = (const float*)d_in[1];   // tgt_embedding [B,D,M]
    const float* src = (const float*)d_in[2];   // src [B,3,N]
    const float* tg  = (const float*)d_in[3];   // tgt [B,3,M]
    float* out = (float*)d_out;

    const size_t embElems = (size_t)B_ * M_ * D_;             // 2M elems (4MB bf16)
    const size_t embBytes = 2 * embElems * 2;                 // 8 MB (q+k)
    const size_t thBytes  = (size_t)B_ * 256 * 512;           // 1 MB swizzled th
    const size_t partB8   = (size_t)8 * B_ * 4 * N_ * 4;      // 4 MB
    const size_t needSwz  = embBytes + thBytes + partB8;      // ~13 MB
    const size_t needOld  = embBytes + partB8;                // ~12 MB

    unsigned short* kb16 = (unsigned short*)d_ws;
    unsigned short* qb16 = kb16 + embElems;
    __fp16* thswz = (__fp16*)((char*)d_ws + embBytes);
    float* partialsNew = (float*)((char*)d_ws + embBytes + thBytes);
    float* partialsOld = (float*)((char*)d_ws + embBytes);

    if (ws_size >= needSwz) {
        prep_all_kernel<<<864, 256, 0, stream>>>(qe, ke, (const float4*)src, tg,
                                                 qb16, kb16, (float4*)out, thswz);
        dim3 grid(N_/256, 8, B_);   // 1024 blocks x 4 waves = 16 waves/CU
        attn10_kernel<8><<<grid, 256, 0, stream>>>(qb16, kb16, thswz, partialsNew);
        finalize_kernel<8><<<(B_*N_)/256, 256, 0, stream>>>(partialsNew, out);
    } else if (ws_size >= needOld) {
        copy_kernel<<<96, 256, 0, stream>>>((const float4*)src, (float4*)out);
        prep_kernel<<<1024, 64, 0, stream>>>(qe, ke, qb16, kb16);
        dim3 grid(N_/64, 8, B_);
        attn2_kernel<8><<<grid, 64, 0, stream>>>(qb16, kb16, tg, partialsOld);
        finalize_kernel<8><<<(B_*N_)/256, 256, 0, stream>>>(partialsOld, out);
    }
}